// Round 21
// baseline (381.529 us; speedup 1.0000x reference)
//
#include <hip/hip_runtime.h>
#include <hip/hip_bf16.h>
#include <math.h>

#define N_NODES 20000
#define N_EDGES 320000
#define NODE_DIM 64
#define EDGE_DIM 32
#define HID 128
#define HEADS 4
#define HC1 512   // HEADS*HID
#define NEG_SLOPE 0.2f

typedef __attribute__((ext_vector_type(8))) short bf16x8;
typedef __attribute__((ext_vector_type(4))) float f32x4;

// hardware bf16 convert (RNE)
__device__ __forceinline__ unsigned short f2b(float f) {
  __hip_bfloat16 h = __float2bfloat16(f);
  unsigned short s;
  __builtin_memcpy(&s, &h, 2);
  return s;
}
__device__ __forceinline__ float b2f(unsigned short b) {
  return __uint_as_float(((unsigned)b) << 16);
}

// ---------------- prologue: ea->bf16 conversion + degree count ----------------
__global__ void prep_kernel(const float* __restrict__ ea, unsigned short* __restrict__ eab,
                            const int* __restrict__ dsts, int* __restrict__ deg)
{
  int i = blockIdx.x * blockDim.x + threadIdx.x;   // 5000*256 = 1.28M
  if (i < N_EDGES * EDGE_DIM / 8) {
    float4 a = *(const float4*)&ea[(size_t)i * 8];
    float4 b = *(const float4*)&ea[(size_t)i * 8 + 4];
    ushort4 u0, u1;
    u0.x = f2b(a.x); u0.y = f2b(a.y); u0.z = f2b(a.z); u0.w = f2b(a.w);
    u1.x = f2b(b.x); u1.y = f2b(b.y); u1.z = f2b(b.z); u1.w = f2b(b.w);
    *(ushort4*)&eab[(size_t)i * 8]     = u0;
    *(ushort4*)&eab[(size_t)i * 8 + 4] = u1;
  }
  if (i < N_EDGES) atomicAdd(&deg[dsts[i]], 1);
}

__global__ __launch_bounds__(1024) void scan_kernel(
    const int* __restrict__ deg, int* __restrict__ offs, int* __restrict__ cursor)
{
  __shared__ int part[1024];
  int t = threadIdx.x;
  const int C = 20;                 // 1024*20 = 20480 >= N_NODES
  int base = t * C;
  int loc[C]; int s = 0;
  #pragma unroll
  for (int i = 0; i < C; i++) { loc[i] = s; int idx = base + i; s += (idx < N_NODES) ? deg[idx] : 0; }
  part[t] = s;
  __syncthreads();
  for (int off = 1; off < 1024; off <<= 1) {
    int v = (t >= off) ? part[t - off] : 0;
    __syncthreads();
    part[t] += v;
    __syncthreads();
  }
  int pbase = (t > 0) ? part[t - 1] : 0;
  #pragma unroll
  for (int i = 0; i < C; i++) {
    int idx = base + i;
    if (idx < N_NODES) { int o = pbase + loc[i]; offs[idx] = o; cursor[idx] = o; }
  }
  if (t == 1023) offs[N_NODES] = part[1023];
}

__global__ void scatter_kernel(const int* __restrict__ dsts, int* __restrict__ cursor,
                               int* __restrict__ csr) {
  int e = blockIdx.x * blockDim.x + threadIdx.x;
  if (e >= N_EDGES) return;
  int pos = atomicAdd(&cursor[dsts[e]], 1);
  csr[pos] = e;
}

// ---------------- weight pre-conversion to bf16 col-major [col][k] ----------------
__global__ void wconv_kernel(const float* __restrict__ Wl1, const float* __restrict__ Wr1,
                             const float* __restrict__ Wl2, const float* __restrict__ Wr2,
                             unsigned short* __restrict__ WT1, unsigned short* __restrict__ WT2)
{
  int i = blockIdx.x * blockDim.x + threadIdx.x;
  if (i < 1024 * 64) {          // WT1: 1024 cols (Wl1|Wr1) x 64 k
    int col = i >> 6, k = i & 63;
    float v = (col < 512) ? Wl1[(size_t)k * HC1 + col] : Wr1[(size_t)k * HC1 + col - 512];
    WT1[i] = f2b(v);
  }
  if (i < 256 * 512) {          // WT2: 256 cols (Wl2|Wr2) x 512 k
    int col = i >> 9, k = i & 511;
    float v = (col < 128) ? Wl2[(size_t)k * HID + col] : Wr2[(size_t)k * HID + col - 128];
    WT2[i] = f2b(v);
  }
}

// ---------------- linear1 (MFMA): xl, xr f32 ----------------
__global__ __launch_bounds__(256, 4) void linear1_kernel(
    const float* __restrict__ x, const unsigned short* __restrict__ WT1,
    const float* __restrict__ bl, const float* __restrict__ br,
    float* __restrict__ xl, float* __restrict__ xr)
{
  __shared__ short xs[16 * 72];   // 16 nodes x 64 k (pad to 72)
  int t = threadIdx.x;
  int n0 = blockIdx.x * 16;
  {
    int i = t * 4;
    int node = i >> 6, k = i & 63;
    float4 v = *(const float4*)&x[(size_t)(n0 + node) * NODE_DIM + k];
    short* d = &xs[node * 72 + k];
    d[0] = (short)f2b(v.x); d[1] = (short)f2b(v.y);
    d[2] = (short)f2b(v.z); d[3] = (short)f2b(v.w);
  }
  __syncthreads();
  int wave = t >> 6, lane = t & 63;
  int l15 = lane & 15, l16 = lane >> 4;
  bf16x8 a0 = *(bf16x8*)&xs[l15 * 72 + 0  + l16 * 8];
  bf16x8 a1 = *(bf16x8*)&xs[l15 * 72 + 32 + l16 * 8];
  #pragma unroll 4
  for (int tt = 0; tt < 16; tt++) {
    int col = wave * 256 + tt * 16 + l15;
    const unsigned short* wp = &WT1[(size_t)col * 64 + l16 * 8];
    bf16x8 b0 = *(bf16x8*)&wp[0];
    bf16x8 b1 = *(bf16x8*)&wp[32];
    f32x4 acc = {0.f, 0.f, 0.f, 0.f};
    acc = __builtin_amdgcn_mfma_f32_16x16x32_bf16(a0, b0, acc, 0, 0, 0);
    acc = __builtin_amdgcn_mfma_f32_16x16x32_bf16(a1, b1, acc, 0, 0, 0);
    float bv = (col < 512) ? bl[col] : br[col - 512];
    float* outp = (col < 512) ? xl : xr;
    int cc = (col < 512) ? col : col - 512;
    #pragma unroll
    for (int r = 0; r < 4; r++)
      outp[(size_t)(n0 + l16 * 4 + r) * HC1 + cc] = acc[r] + bv;
  }
}

// ---------------- fused layer 1 (bf16 ea copies; wave-stride nodes) ----------------
// grid = 1024 blocks (2 halves x 512); block = 512 = 8 waves.
__global__ __launch_bounds__(512, 2) void fused1_kernel(
    const unsigned short* __restrict__ eab, const int* __restrict__ srcs,
    const float* __restrict__ We, const float* __restrict__ att,
    const float* __restrict__ xl, const float* __restrict__ xr,
    const float* __restrict__ bias, const int* __restrict__ offs,
    const int* __restrict__ csr, unsigned short* __restrict__ h1b)
{
  __shared__ short WtT[256 * 40];        // 20KB
  __shared__ short easb[8][16 * 40];     // 10KB
  __shared__ short ee_b[8][8][264];      // 33KB
  int t = threadIdx.x;
  int half = blockIdx.x & 1;
  for (int i = t; i < EDGE_DIM * 256; i += 512) {
    int k = i >> 8, c = i & 255;
    WtT[c * 40 + k] = (short)f2b(We[(size_t)k * HC1 + half * 256 + c]);
  }
  __syncthreads();
  int wave = t >> 6, lane = t & 63;
  int l15 = lane & 15, l16 = lane >> 4;
  int g = (blockIdx.x >> 1) * 8 + wave;    // [0, 4096)
  int Cl = lane * 4;
  int C = half * 256 + Cl;
  float at4[4];
  *(float4*)at4 = *(const float4*)&att[C];
  for (int n = g; n < N_NODES; n += 4096) {
    float xr4[4];
    *(float4*)xr4 = *(const float4*)&xr[(size_t)n * HC1 + C];
    float o4[4] = {0.f,0.f,0.f,0.f};
    float mx = 8.0f, dn = 0.f;
    int beg = offs[n], end = offs[n + 1];
    int ev = 0, sv = 0;
    if (lane < 8 && beg + lane < end) { ev = csr[beg + lane]; sv = srcs[ev]; }
    for (int i0 = beg; i0 < end; i0 += 8) {
      int nv = end - i0; if (nv > 8) nv = 8;
      int sarr[8];
      #pragma unroll
      for (int j = 0; j < 8; j++) sarr[j] = __shfl(sv, j);
      // xl gathers issued first (f32, 16B/lane)
      float xv[8][4];
      #pragma unroll
      for (int j = 0; j < 8; j++) {
        if (j < nv) *(float4*)&xv[j][0] = *(const float4*)&xl[(size_t)sarr[j] * HC1 + C];
        else { xv[j][0] = 0.f; xv[j][1] = 0.f; xv[j][2] = 0.f; xv[j][3] = 0.f; }
      }
      // stage 8 bf16 ea rows: pure 16B copies (lanes 0-31)
      {
        int me = __shfl(ev, lane >> 2);
        if (lane < 32) {
          int q = lane & 3;
          bf16x8 v = *(const bf16x8*)&eab[(size_t)me * EDGE_DIM + q * 8];
          *(bf16x8*)&easb[wave][(lane >> 2) * 40 + q * 8] = v;
        }
      }
      // prefetch next chunk's indices
      if (lane < 8 && i0 + 8 + lane < end) { ev = csr[i0 + 8 + lane]; sv = srcs[ev]; }
      bf16x8 bfrag = *(bf16x8*)&easb[wave][l15 * 40 + l16 * 8];
      #pragma unroll 4
      for (int tt = 0; tt < 16; tt++) {
        bf16x8 afrag = *(bf16x8*)&WtT[(tt * 16 + l15) * 40 + l16 * 8];
        f32x4 cz = {0.f, 0.f, 0.f, 0.f};
        f32x4 cv = __builtin_amdgcn_mfma_f32_16x16x32_bf16(afrag, bfrag, cz, 0, 0, 0);
        if (l15 < 8) {
          ushort4 u;
          u.x = f2b(cv[0]); u.y = f2b(cv[1]); u.z = f2b(cv[2]); u.w = f2b(cv[3]);
          *(ushort4*)&ee_b[wave][l15][tt * 16 + l16 * 4] = u;
        }
      }
      float pl[8];
      #pragma unroll
      for (int j = 0; j < 8; j++) {
        ushort4 ub = *(const ushort4*)&ee_b[wave][j][Cl];
        float z0 = b2f(ub.x) + xv[j][0] + xr4[0];
        float z1 = b2f(ub.y) + xv[j][1] + xr4[1];
        float z2 = b2f(ub.z) + xv[j][2] + xr4[2];
        float z3 = b2f(ub.w) + xv[j][3] + xr4[3];
        z0 = z0 > 0.f ? z0 : NEG_SLOPE * z0;
        z1 = z1 > 0.f ? z1 : NEG_SLOPE * z1;
        z2 = z2 > 0.f ? z2 : NEG_SLOPE * z2;
        z3 = z3 > 0.f ? z3 : NEG_SLOPE * z3;
        float s = ((z0 * at4[0] + z1 * at4[1]) + (z2 * at4[2] + z3 * at4[3]));
        #pragma unroll
        for (int o = 1; o <= 16; o <<= 1) s += __shfl_xor(s, o);
        pl[j] = (j < nv) ? s : -3.0e38f;
      }
      float cm = fmaxf(fmaxf(fmaxf(pl[0], pl[1]), fmaxf(pl[2], pl[3])),
                       fmaxf(fmaxf(pl[4], pl[5]), fmaxf(pl[6], pl[7])));
      float mn = fmaxf(mx, cm);
      if (__any(mn > mx + 8.f)) {
        float fs = __expf(mx - mn);
        dn *= fs;
        #pragma unroll
        for (int c = 0; c < 4; c++) o4[c] *= fs;
        mx = mn;
      }
      float p[8];
      #pragma unroll
      for (int j = 0; j < 8; j++) p[j] = __expf(pl[j] - mx);
      dn += ((p[0] + p[1]) + (p[2] + p[3])) + ((p[4] + p[5]) + (p[6] + p[7]));
      #pragma unroll
      for (int c = 0; c < 4; c++) {
        float acc = 0.f;
        #pragma unroll
        for (int j = 0; j < 8; j++) acc = fmaf(p[j], xv[j][c], acc);
        o4[c] += acc;
      }
    }
    float iv = dn > 0.f ? 1.f / dn : 0.f;
    ushort4 u;
    float v0 = o4[0] * iv + bias[C + 0]; v0 = v0 > 0.f ? v0 : 0.f;
    float v1 = o4[1] * iv + bias[C + 1]; v1 = v1 > 0.f ? v1 : 0.f;
    float v2 = o4[2] * iv + bias[C + 2]; v2 = v2 > 0.f ? v2 : 0.f;
    float v3 = o4[3] * iv + bias[C + 3]; v3 = v3 > 0.f ? v3 : 0.f;
    u.x = f2b(v0); u.y = f2b(v1); u.z = f2b(v2); u.w = f2b(v3);
    *(ushort4*)&h1b[(size_t)n * HC1 + C] = u;    // relu'd, bf16
  }
}

// ---------------- linear2 (MFMA, bf16 in, f32 out) ----------------
__global__ __launch_bounds__(256, 4) void linear2_kernel(
    const unsigned short* __restrict__ hin, const unsigned short* __restrict__ WT2,
    const float* __restrict__ bl, const float* __restrict__ br,
    float* __restrict__ xl2, float* __restrict__ xr2)
{
  __shared__ short hs[16 * 520];   // 16 nodes x 512 k (pad to 520) bf16 = 16.6KB
  int t = threadIdx.x;
  int n0 = blockIdx.x * 16;
  for (int rr = 0; rr < 8; rr++) {
    int i = (t + rr * 256) * 4;
    int node = i >> 9, k = i & 511;
    short* d = &hs[node * 520 + k];
    ushort4 u = *(const ushort4*)&hin[(size_t)(n0 + node) * HC1 + k];
    d[0] = (short)u.x; d[1] = (short)u.y; d[2] = (short)u.z; d[3] = (short)u.w;
  }
  __syncthreads();
  int wave = t >> 6, lane = t & 63;
  int l15 = lane & 15, l16 = lane >> 4;
  f32x4 acc0 = {0.f,0.f,0.f,0.f}, acc1 = {0.f,0.f,0.f,0.f};
  f32x4 acc2 = {0.f,0.f,0.f,0.f}, acc3 = {0.f,0.f,0.f,0.f};
  int colb = wave * 64 + l15;
  #pragma unroll 2
  for (int ks = 0; ks < 16; ks++) {
    bf16x8 a = *(bf16x8*)&hs[l15 * 520 + ks * 32 + l16 * 8];
    bf16x8 b0 = *(bf16x8*)&WT2[(size_t)(colb +  0) * 512 + ks * 32 + l16 * 8];
    bf16x8 b1 = *(bf16x8*)&WT2[(size_t)(colb + 16) * 512 + ks * 32 + l16 * 8];
    bf16x8 b2 = *(bf16x8*)&WT2[(size_t)(colb + 32) * 512 + ks * 32 + l16 * 8];
    bf16x8 b3 = *(bf16x8*)&WT2[(size_t)(colb + 48) * 512 + ks * 32 + l16 * 8];
    acc0 = __builtin_amdgcn_mfma_f32_16x16x32_bf16(a, b0, acc0, 0, 0, 0);
    acc1 = __builtin_amdgcn_mfma_f32_16x16x32_bf16(a, b1, acc1, 0, 0, 0);
    acc2 = __builtin_amdgcn_mfma_f32_16x16x32_bf16(a, b2, acc2, 0, 0, 0);
    acc3 = __builtin_amdgcn_mfma_f32_16x16x32_bf16(a, b3, acc3, 0, 0, 0);
  }
  #pragma unroll
  for (int tt = 0; tt < 4; tt++) {
    const f32x4* ap = (tt == 0) ? &acc0 : (tt == 1) ? &acc1 : (tt == 2) ? &acc2 : &acc3;
    int col = wave * 64 + tt * 16 + l15;
    float bv = (col < 128) ? bl[col] : br[col - 128];
    float* outp = (col < 128) ? xl2 : xr2;
    int cc = (col < 128) ? col : col - 128;
    #pragma unroll
    for (int r = 0; r < 4; r++)
      outp[(size_t)(n0 + l16 * 4 + r) * HID + cc] = (*ap)[r] + bv;
  }
}

// ---------------- fused layer 2 (bf16 ea copies; wave-stride nodes) ----------------
// grid = 512 blocks; wave g = blockIdx*8+wave handles nodes g, g+4096, ...
__global__ __launch_bounds__(512, 2) void fused2_kernel(
    const unsigned short* __restrict__ eab, const int* __restrict__ srcs,
    const float* __restrict__ We, const float* __restrict__ att,
    const float* __restrict__ xl, const float* __restrict__ xr,
    const float* __restrict__ bias, const int* __restrict__ offs,
    const int* __restrict__ csr, float* __restrict__ h2out)
{
  __shared__ short W2tT[HID * 40];       // 10KB
  __shared__ short easb2[8][16 * 40];    // 10KB, all 16 rows real
  __shared__ short ee2b[8][16][136];     // 34.8KB
  int t = threadIdx.x;
  for (int i = t; i < EDGE_DIM * HID; i += 512) {
    int k = i >> 7, c = i & 127;
    W2tT[c * 40 + k] = (short)f2b(We[(size_t)k * HID + c]);
  }
  __syncthreads();
  int wave = t >> 6, lane = t & 63;
  int l15 = lane & 15, l16 = lane >> 4;
  int g = blockIdx.x * 8 + wave;          // [0, 4096)
  int c = lane * 2;
  float2 atv = *(const float2*)&att[c];
  for (int n = g; n < N_NODES; n += 4096) {
    float2 xrv = *(const float2*)&xr[(size_t)n * HID + c];
    float oa = 0.f, ob = 0.f;
    float m = 8.0f, d = 0.f;
    int beg = offs[n], end = offs[n + 1];
    int ev = 0, sv = 0;
    if (lane < 16 && beg + lane < end) { ev = csr[beg + lane]; sv = srcs[ev]; }
    for (int i0 = beg; i0 < end; i0 += 16) {
      int nv = end - i0; if (nv > 16) nv = 16;
      int sarr[16];
      #pragma unroll
      for (int j = 0; j < 16; j++) sarr[j] = __shfl(sv, j);
      float2 xv[16];
      #pragma unroll
      for (int j = 0; j < 16; j++) {
        if (j < nv) xv[j] = *(const float2*)&xl[(size_t)sarr[j] * HID + c];
        else { xv[j].x = 0.f; xv[j].y = 0.f; }
      }
      // stage 16 bf16 ea rows: pure 16B copies (all 64 lanes)
      {
        int me = __shfl(ev, lane >> 2);
        int q = lane & 3;
        bf16x8 v = *(const bf16x8*)&eab[(size_t)me * EDGE_DIM + q * 8];
        *(bf16x8*)&easb2[wave][(lane >> 2) * 40 + q * 8] = v;
      }
      if (lane < 16 && i0 + 16 + lane < end) { ev = csr[i0 + 16 + lane]; sv = srcs[ev]; }
      bf16x8 bfrag = *(bf16x8*)&easb2[wave][l15 * 40 + l16 * 8];
      #pragma unroll 4
      for (int tt = 0; tt < 8; tt++) {
        bf16x8 afrag = *(bf16x8*)&W2tT[(tt * 16 + l15) * 40 + l16 * 8];
        f32x4 cz = {0.f, 0.f, 0.f, 0.f};
        f32x4 cv = __builtin_amdgcn_mfma_f32_16x16x32_bf16(afrag, bfrag, cz, 0, 0, 0);
        ushort4 u;
        u.x = f2b(cv[0]); u.y = f2b(cv[1]); u.z = f2b(cv[2]); u.w = f2b(cv[3]);
        *(ushort4*)&ee2b[wave][l15][tt * 16 + l16 * 4] = u;
      }
      float pl[16];
      #pragma unroll
      for (int j = 0; j < 16; j++) {
        ushort2 uv = *(const ushort2*)&ee2b[wave][j][c];
        float za = b2f(uv.x) + xv[j].x + xrv.x;
        float zb = b2f(uv.y) + xv[j].y + xrv.y;
        za = za > 0.f ? za : NEG_SLOPE * za;
        zb = zb > 0.f ? zb : NEG_SLOPE * zb;
        float s = za * atv.x + zb * atv.y;
        #pragma unroll
        for (int o = 1; o < 64; o <<= 1) s += __shfl_xor(s, o);
        pl[j] = (j < nv) ? s : -3.0e38f;
      }
      float cm = pl[0];
      #pragma unroll
      for (int j = 1; j < 16; j++) cm = fmaxf(cm, pl[j]);
      float mn = fmaxf(m, cm);
      if (__any(mn > m + 8.f)) {
        float fs = __expf(m - mn);
        d *= fs; oa *= fs; ob *= fs;
        m = mn;
      }
      #pragma unroll
      for (int j = 0; j < 16; j++) {
        float p = __expf(pl[j] - m);
        d += p;
        oa = fmaf(p, xv[j].x, oa);
        ob = fmaf(p, xv[j].y, ob);
      }
    }
    float invd = d > 0.f ? 1.f / d : 0.f;
    float2 o2 = make_float2(oa * invd + bias[c], ob * invd + bias[c + 1]); // no relu after conv2
    *(float2*)&h2out[(size_t)n * HID + c] = o2;
  }
}

// ---------------- MLP head ----------------
__global__ __launch_bounds__(256) void head_kernel(
    const float* __restrict__ h2, const float* __restrict__ Wh1,
    const float* __restrict__ bh1, const float* __restrict__ Wh2,
    const float* __restrict__ bh2, float* __restrict__ out)
{
  __shared__ float hs[16][HID];   // 8KB
  __shared__ float ts[16][64];    // 4KB
  int n0 = blockIdx.x * 16;
  int t = threadIdx.x;
  for (int r = 0; r < 2; r++) {
    int flat = (t + r * 256) * 4; // 2048 floats
    int i = flat >> 7, k = flat & 127;
    *(float4*)&hs[i][k] = *(const float4*)&h2[(size_t)(n0 + i) * HID + k];
  }
  __syncthreads();
  int j = t & 63, g = t >> 6;
  float acc[4];
  #pragma unroll
  for (int q = 0; q < 4; q++) acc[q] = 0.f;
  for (int k = 0; k < HID; k++) {
    float w = Wh1[k * 64 + j];
    #pragma unroll
    for (int q = 0; q < 4; q++) acc[q] = fmaf(hs[g + 4 * q][k], w, acc[q]);
  }
  float bj = bh1[j];
  #pragma unroll
  for (int q = 0; q < 4; q++) {
    float v = acc[q] + bj;
    ts[g + 4 * q][j] = v > 0.f ? v : 0.f;
  }
  __syncthreads();
  if (t < 32) {
    int nl = t >> 1, k = t & 1;
    float acc2 = bh2[k];
    for (int jj = 0; jj < 64; jj++) acc2 = fmaf(ts[nl][jj], Wh2[jj * 2 + k], acc2);
    out[(size_t)(n0 + nl) * 2 + k] = acc2;
  }
}

extern "C" void kernel_launch(void* const* d_in, const int* in_sizes, int n_in,
                              void* d_out, int out_size, void* d_ws, size_t ws_size,
                              hipStream_t stream)
{
  (void)in_sizes; (void)n_in; (void)out_size; (void)ws_size;
  const float* x    = (const float*)d_in[0];
  const int* eidx   = (const int*)d_in[1];
  const float* ea   = (const float*)d_in[2];
  const float* Wl1  = (const float*)d_in[3];
  const float* bl1  = (const float*)d_in[4];
  const float* Wr1  = (const float*)d_in[5];
  const float* br1  = (const float*)d_in[6];
  const float* We1  = (const float*)d_in[7];
  const float* att1 = (const float*)d_in[8];
  const float* bias1= (const float*)d_in[9];
  const float* Wl2  = (const float*)d_in[10];
  const float* bl2  = (const float*)d_in[11];
  const float* Wr2  = (const float*)d_in[12];
  const float* br2  = (const float*)d_in[13];
  const float* We2  = (const float*)d_in[14];
  const float* att2 = (const float*)d_in[15];
  const float* bias2= (const float*)d_in[16];
  const float* Wh1  = (const float*)d_in[17];
  const float* bh1  = (const float*)d_in[18];
  const float* Wh2  = (const float*)d_in[19];
  const float* bh2  = (const float*)d_in[20];
  const int* srcs = eidx;
  const int* dsts = eidx + N_EDGES;
  float* out = (float*)d_out;

  char* p = (char*)d_ws;
  auto alloc = [&](size_t bytes) { char* q = p; p += (bytes + 511) & ~(size_t)511; return q; };
  float*          xl1  = (float*)alloc((size_t)N_NODES * HC1 * 4);           // 41MB
  float*          xr1  = (float*)alloc((size_t)N_NODES * HC1 * 4);           // 41MB
  unsigned short* h1b  = (unsigned short*)alloc((size_t)N_NODES * HC1 * 2);  // 20.5MB
  unsigned short* eab  = (unsigned short*)alloc((size_t)N_EDGES * EDGE_DIM * 2); // 20.5MB
  int* deg    = (int*)alloc((size_t)N_NODES * 4);
  int* offs   = (int*)alloc((size_t)(N_NODES + 1) * 4);
  int* cursor = (int*)alloc((size_t)N_NODES * 4);
  int* csr    = (int*)alloc((size_t)N_EDGES * 4);
  unsigned short* WT1 = (unsigned short*)alloc(1024 * 64 * 2);
  unsigned short* WT2 = (unsigned short*)alloc(256 * 512 * 2);
  // xl1 region dead after fused1 -> reuse for xl2, xr2, h2 (30.7MB <= 41MB)
  float* xl2 = xl1;
  float* xr2 = xl1 + (size_t)N_NODES * HID;
  float* h2  = xl1 + (size_t)2 * N_NODES * HID;

  hipMemsetAsync(deg, 0, (size_t)N_NODES * 4, stream);
  hipLaunchKernelGGL(prep_kernel, dim3(N_EDGES * EDGE_DIM / 8 / 256), dim3(256), 0, stream,
                     ea, eab, dsts, deg);
  hipLaunchKernelGGL(wconv_kernel, dim3(512), dim3(256), 0, stream, Wl1, Wr1, Wl2, Wr2, WT1, WT2);
  hipLaunchKernelGGL(scan_kernel, dim3(1), dim3(1024), 0, stream, deg, offs, cursor);
  hipLaunchKernelGGL(scatter_kernel, dim3((N_EDGES + 255) / 256), dim3(256), 0, stream, dsts, cursor, csr);
  hipLaunchKernelGGL(linear1_kernel, dim3(N_NODES / 16), dim3(256), 0, stream,
                     x, WT1, bl1, br1, xl1, xr1);
  hipLaunchKernelGGL(fused1_kernel, dim3(1024), dim3(512), 0, stream,
                     eab, srcs, We1, att1, xl1, xr1, bias1, offs, csr, h1b);
  hipLaunchKernelGGL(linear2_kernel, dim3(N_NODES / 16), dim3(256), 0, stream,
                     h1b, WT2, bl2, br2, xl2, xr2);
  hipLaunchKernelGGL(fused2_kernel, dim3(512), dim3(512), 0, stream,
                     eab, srcs, We2, att2, xl2, xr2, bias2, offs, csr, h2);
  hipLaunchKernelGGL(head_kernel, dim3(N_NODES / 16), dim3(256), 0, stream,
                     h2, Wh1, bh1, Wh2, bh2, out);
}

// Round 22
// 372.762 us; speedup vs baseline: 1.0235x; 1.0235x over previous
//
#include <hip/hip_runtime.h>
#include <hip/hip_bf16.h>
#include <math.h>

#define N_NODES 20000
#define N_EDGES 320000
#define NODE_DIM 64
#define EDGE_DIM 32
#define HID 128
#define HEADS 4
#define HC1 512   // HEADS*HID
#define NEG_SLOPE 0.2f

typedef __attribute__((ext_vector_type(8))) short bf16x8;
typedef __attribute__((ext_vector_type(4))) float f32x4;

// hardware bf16 convert (RNE)
__device__ __forceinline__ unsigned short f2b(float f) {
  __hip_bfloat16 h = __float2bfloat16(f);
  unsigned short s;
  __builtin_memcpy(&s, &h, 2);
  return s;
}
__device__ __forceinline__ float b2f(unsigned short b) {
  return __uint_as_float(((unsigned)b) << 16);
}

// ---------------- CSR build ----------------
__global__ void deg_count_kernel(const int* __restrict__ dsts, int* __restrict__ deg) {
  int e = blockIdx.x * blockDim.x + threadIdx.x;
  if (e < N_EDGES) atomicAdd(&deg[dsts[e]], 1);
}

__global__ __launch_bounds__(1024) void scan_kernel(
    const int* __restrict__ deg, int* __restrict__ offs, int* __restrict__ cursor)
{
  __shared__ int part[1024];
  int t = threadIdx.x;
  const int C = 20;                 // 1024*20 = 20480 >= N_NODES
  int base = t * C;
  int loc[C]; int s = 0;
  #pragma unroll
  for (int i = 0; i < C; i++) { loc[i] = s; int idx = base + i; s += (idx < N_NODES) ? deg[idx] : 0; }
  part[t] = s;
  __syncthreads();
  for (int off = 1; off < 1024; off <<= 1) {
    int v = (t >= off) ? part[t - off] : 0;
    __syncthreads();
    part[t] += v;
    __syncthreads();
  }
  int pbase = (t > 0) ? part[t - 1] : 0;
  #pragma unroll
  for (int i = 0; i < C; i++) {
    int idx = base + i;
    if (idx < N_NODES) { int o = pbase + loc[i]; offs[idx] = o; cursor[idx] = o; }
  }
  if (t == 1023) offs[N_NODES] = part[1023];
}

__global__ void scatter_kernel(const int* __restrict__ dsts, int* __restrict__ cursor,
                               int* __restrict__ csr) {
  int e = blockIdx.x * blockDim.x + threadIdx.x;
  if (e >= N_EDGES) return;
  int pos = atomicAdd(&cursor[dsts[e]], 1);
  csr[pos] = e;
}

// ---------------- weight pre-conversion to bf16 col-major [col][k] ----------------
__global__ void wconv_kernel(const float* __restrict__ Wl1, const float* __restrict__ Wr1,
                             const float* __restrict__ Wl2, const float* __restrict__ Wr2,
                             unsigned short* __restrict__ WT1, unsigned short* __restrict__ WT2)
{
  int i = blockIdx.x * blockDim.x + threadIdx.x;
  if (i < 1024 * 64) {          // WT1: 1024 cols (Wl1|Wr1) x 64 k
    int col = i >> 6, k = i & 63;
    float v = (col < 512) ? Wl1[(size_t)k * HC1 + col] : Wr1[(size_t)k * HC1 + col - 512];
    WT1[i] = f2b(v);
  }
  if (i < 256 * 512) {          // WT2: 256 cols (Wl2|Wr2) x 512 k
    int col = i >> 9, k = i & 511;
    float v = (col < 128) ? Wl2[(size_t)k * HID + col] : Wr2[(size_t)k * HID + col - 128];
    WT2[i] = f2b(v);
  }
}

// ---------------- linear1 (MFMA): xl, xr f32 ----------------
__global__ __launch_bounds__(256, 4) void linear1_kernel(
    const float* __restrict__ x, const unsigned short* __restrict__ WT1,
    const float* __restrict__ bl, const float* __restrict__ br,
    float* __restrict__ xl, float* __restrict__ xr)
{
  __shared__ short xs[16 * 72];   // 16 nodes x 64 k (pad to 72)
  int t = threadIdx.x;
  int n0 = blockIdx.x * 16;
  {
    int i = t * 4;
    int node = i >> 6, k = i & 63;
    float4 v = *(const float4*)&x[(size_t)(n0 + node) * NODE_DIM + k];
    short* d = &xs[node * 72 + k];
    d[0] = (short)f2b(v.x); d[1] = (short)f2b(v.y);
    d[2] = (short)f2b(v.z); d[3] = (short)f2b(v.w);
  }
  __syncthreads();
  int wave = t >> 6, lane = t & 63;
  int l15 = lane & 15, l16 = lane >> 4;
  bf16x8 a0 = *(bf16x8*)&xs[l15 * 72 + 0  + l16 * 8];
  bf16x8 a1 = *(bf16x8*)&xs[l15 * 72 + 32 + l16 * 8];
  #pragma unroll 4
  for (int tt = 0; tt < 16; tt++) {
    int col = wave * 256 + tt * 16 + l15;
    const unsigned short* wp = &WT1[(size_t)col * 64 + l16 * 8];
    bf16x8 b0 = *(bf16x8*)&wp[0];
    bf16x8 b1 = *(bf16x8*)&wp[32];
    f32x4 acc = {0.f, 0.f, 0.f, 0.f};
    acc = __builtin_amdgcn_mfma_f32_16x16x32_bf16(a0, b0, acc, 0, 0, 0);
    acc = __builtin_amdgcn_mfma_f32_16x16x32_bf16(a1, b1, acc, 0, 0, 0);
    float bv = (col < 512) ? bl[col] : br[col - 512];
    float* outp = (col < 512) ? xl : xr;
    int cc = (col < 512) ? col : col - 512;
    #pragma unroll
    for (int r = 0; r < 4; r++)
      outp[(size_t)(n0 + l16 * 4 + r) * HC1 + cc] = acc[r] + bv;
  }
}

// ---------------- fused layer 1 (R20 structure + setprio around MFMA) ----------------
// grid = 1024 blocks (2 halves x 512); block = 512 = 8 waves; wave-stride nodes.
__global__ __launch_bounds__(512, 2) void fused1_kernel(
    const float* __restrict__ ea, const int* __restrict__ srcs,
    const float* __restrict__ We, const float* __restrict__ att,
    const float* __restrict__ xl, const float* __restrict__ xr,
    const float* __restrict__ bias, const int* __restrict__ offs,
    const int* __restrict__ csr, unsigned short* __restrict__ h1b)
{
  __shared__ short WtT[256 * 40];        // 20KB
  __shared__ short easb[8][16 * 40];     // 10KB
  __shared__ short ee_b[8][8][264];      // 33KB
  int t = threadIdx.x;
  int half = blockIdx.x & 1;
  for (int i = t; i < EDGE_DIM * 256; i += 512) {
    int k = i >> 8, c = i & 255;
    WtT[c * 40 + k] = (short)f2b(We[(size_t)k * HC1 + half * 256 + c]);
  }
  __syncthreads();
  int wave = t >> 6, lane = t & 63;
  int l15 = lane & 15, l16 = lane >> 4;
  int g = (blockIdx.x >> 1) * 8 + wave;    // [0, 4096)
  int Cl = lane * 4;
  int C = half * 256 + Cl;
  float at4[4];
  *(float4*)at4 = *(const float4*)&att[C];
  for (int n = g; n < N_NODES; n += 4096) {
    float xr4[4];
    *(float4*)xr4 = *(const float4*)&xr[(size_t)n * HC1 + C];
    float o4[4] = {0.f,0.f,0.f,0.f};
    float mx = 8.0f, dn = 0.f;
    int beg = offs[n], end = offs[n + 1];
    int ev = 0, sv = 0;
    if (lane < 8 && beg + lane < end) { ev = csr[beg + lane]; sv = srcs[ev]; }
    for (int i0 = beg; i0 < end; i0 += 8) {
      int nv = end - i0; if (nv > 8) nv = 8;
      int sarr[8];
      #pragma unroll
      for (int j = 0; j < 8; j++) sarr[j] = __shfl(sv, j);
      // xl gathers issued first (f32, 16B/lane)
      float xv[8][4];
      #pragma unroll
      for (int j = 0; j < 8; j++) {
        if (j < nv) *(float4*)&xv[j][0] = *(const float4*)&xl[(size_t)sarr[j] * HC1 + C];
        else { xv[j][0] = 0.f; xv[j][1] = 0.f; xv[j][2] = 0.f; xv[j][3] = 0.f; }
      }
      // stage the chunk's 8 ea rows as bf16 (lanes 0-31)
      {
        int me = __shfl(ev, lane >> 2);
        if (lane < 32) {
          int q = lane & 3;
          float4 u0 = *(const float4*)&ea[(size_t)me * EDGE_DIM + q * 8];
          float4 u1 = *(const float4*)&ea[(size_t)me * EDGE_DIM + q * 8 + 4];
          short* dst = &easb[wave][(lane >> 2) * 40 + q * 8];
          dst[0] = (short)f2b(u0.x); dst[1] = (short)f2b(u0.y);
          dst[2] = (short)f2b(u0.z); dst[3] = (short)f2b(u0.w);
          dst[4] = (short)f2b(u1.x); dst[5] = (short)f2b(u1.y);
          dst[6] = (short)f2b(u1.z); dst[7] = (short)f2b(u1.w);
        }
      }
      // prefetch next chunk's indices
      if (lane < 8 && i0 + 8 + lane < end) { ev = csr[i0 + 8 + lane]; sv = srcs[ev]; }
      bf16x8 bfrag = *(bf16x8*)&easb[wave][l15 * 40 + l16 * 8];
      __builtin_amdgcn_s_setprio(1);     // prefer MFMA-entering waves (T5)
      #pragma unroll 4
      for (int tt = 0; tt < 16; tt++) {
        bf16x8 afrag = *(bf16x8*)&WtT[(tt * 16 + l15) * 40 + l16 * 8];
        f32x4 cz = {0.f, 0.f, 0.f, 0.f};
        f32x4 cv = __builtin_amdgcn_mfma_f32_16x16x32_bf16(afrag, bfrag, cz, 0, 0, 0);
        if (l15 < 8) {
          ushort4 u;
          u.x = f2b(cv[0]); u.y = f2b(cv[1]); u.z = f2b(cv[2]); u.w = f2b(cv[3]);
          *(ushort4*)&ee_b[wave][l15][tt * 16 + l16 * 4] = u;
        }
      }
      __builtin_amdgcn_s_setprio(0);
      float pl[8];
      #pragma unroll
      for (int j = 0; j < 8; j++) {
        ushort4 ub = *(const ushort4*)&ee_b[wave][j][Cl];
        float z0 = b2f(ub.x) + xv[j][0] + xr4[0];
        float z1 = b2f(ub.y) + xv[j][1] + xr4[1];
        float z2 = b2f(ub.z) + xv[j][2] + xr4[2];
        float z3 = b2f(ub.w) + xv[j][3] + xr4[3];
        z0 = z0 > 0.f ? z0 : NEG_SLOPE * z0;
        z1 = z1 > 0.f ? z1 : NEG_SLOPE * z1;
        z2 = z2 > 0.f ? z2 : NEG_SLOPE * z2;
        z3 = z3 > 0.f ? z3 : NEG_SLOPE * z3;
        float s = ((z0 * at4[0] + z1 * at4[1]) + (z2 * at4[2] + z3 * at4[3]));
        #pragma unroll
        for (int o = 1; o <= 16; o <<= 1) s += __shfl_xor(s, o);
        pl[j] = (j < nv) ? s : -3.0e38f;
      }
      float cm = fmaxf(fmaxf(fmaxf(pl[0], pl[1]), fmaxf(pl[2], pl[3])),
                       fmaxf(fmaxf(pl[4], pl[5]), fmaxf(pl[6], pl[7])));
      float mn = fmaxf(mx, cm);
      if (__any(mn > mx + 8.f)) {
        float fs = __expf(mx - mn);
        dn *= fs;
        #pragma unroll
        for (int c = 0; c < 4; c++) o4[c] *= fs;
        mx = mn;
      }
      float p[8];
      #pragma unroll
      for (int j = 0; j < 8; j++) p[j] = __expf(pl[j] - mx);
      dn += ((p[0] + p[1]) + (p[2] + p[3])) + ((p[4] + p[5]) + (p[6] + p[7]));
      #pragma unroll
      for (int c = 0; c < 4; c++) {
        float acc = 0.f;
        #pragma unroll
        for (int j = 0; j < 8; j++) acc = fmaf(p[j], xv[j][c], acc);
        o4[c] += acc;
      }
    }
    float iv = dn > 0.f ? 1.f / dn : 0.f;
    ushort4 u;
    float v0 = o4[0] * iv + bias[C + 0]; v0 = v0 > 0.f ? v0 : 0.f;
    float v1 = o4[1] * iv + bias[C + 1]; v1 = v1 > 0.f ? v1 : 0.f;
    float v2 = o4[2] * iv + bias[C + 2]; v2 = v2 > 0.f ? v2 : 0.f;
    float v3 = o4[3] * iv + bias[C + 3]; v3 = v3 > 0.f ? v3 : 0.f;
    u.x = f2b(v0); u.y = f2b(v1); u.z = f2b(v2); u.w = f2b(v3);
    *(ushort4*)&h1b[(size_t)n * HC1 + C] = u;    // relu'd, bf16
  }
}

// ---------------- linear2 (MFMA, bf16 in, f32 out) ----------------
__global__ __launch_bounds__(256, 4) void linear2_kernel(
    const unsigned short* __restrict__ hin, const unsigned short* __restrict__ WT2,
    const float* __restrict__ bl, const float* __restrict__ br,
    float* __restrict__ xl2, float* __restrict__ xr2)
{
  __shared__ short hs[16 * 520];   // 16 nodes x 512 k (pad to 520) bf16 = 16.6KB
  int t = threadIdx.x;
  int n0 = blockIdx.x * 16;
  for (int rr = 0; rr < 8; rr++) {
    int i = (t + rr * 256) * 4;
    int node = i >> 9, k = i & 511;
    short* d = &hs[node * 520 + k];
    ushort4 u = *(const ushort4*)&hin[(size_t)(n0 + node) * HC1 + k];
    d[0] = (short)u.x; d[1] = (short)u.y; d[2] = (short)u.z; d[3] = (short)u.w;
  }
  __syncthreads();
  int wave = t >> 6, lane = t & 63;
  int l15 = lane & 15, l16 = lane >> 4;
  f32x4 acc0 = {0.f,0.f,0.f,0.f}, acc1 = {0.f,0.f,0.f,0.f};
  f32x4 acc2 = {0.f,0.f,0.f,0.f}, acc3 = {0.f,0.f,0.f,0.f};
  int colb = wave * 64 + l15;
  #pragma unroll 2
  for (int ks = 0; ks < 16; ks++) {
    bf16x8 a = *(bf16x8*)&hs[l15 * 520 + ks * 32 + l16 * 8];
    bf16x8 b0 = *(bf16x8*)&WT2[(size_t)(colb +  0) * 512 + ks * 32 + l16 * 8];
    bf16x8 b1 = *(bf16x8*)&WT2[(size_t)(colb + 16) * 512 + ks * 32 + l16 * 8];
    bf16x8 b2 = *(bf16x8*)&WT2[(size_t)(colb + 32) * 512 + ks * 32 + l16 * 8];
    bf16x8 b3 = *(bf16x8*)&WT2[(size_t)(colb + 48) * 512 + ks * 32 + l16 * 8];
    acc0 = __builtin_amdgcn_mfma_f32_16x16x32_bf16(a, b0, acc0, 0, 0, 0);
    acc1 = __builtin_amdgcn_mfma_f32_16x16x32_bf16(a, b1, acc1, 0, 0, 0);
    acc2 = __builtin_amdgcn_mfma_f32_16x16x32_bf16(a, b2, acc2, 0, 0, 0);
    acc3 = __builtin_amdgcn_mfma_f32_16x16x32_bf16(a, b3, acc3, 0, 0, 0);
  }
  #pragma unroll
  for (int tt = 0; tt < 4; tt++) {
    const f32x4* ap = (tt == 0) ? &acc0 : (tt == 1) ? &acc1 : (tt == 2) ? &acc2 : &acc3;
    int col = wave * 64 + tt * 16 + l15;
    float bv = (col < 128) ? bl[col] : br[col - 128];
    float* outp = (col < 128) ? xl2 : xr2;
    int cc = (col < 128) ? col : col - 128;
    #pragma unroll
    for (int r = 0; r < 4; r++)
      outp[(size_t)(n0 + l16 * 4 + r) * HID + cc] = (*ap)[r] + bv;
  }
}

// ---------------- fused layer 2 (R20 structure + setprio around MFMA) ----------------
// grid = 512 blocks; wave g = blockIdx*8+wave handles nodes g, g+4096, ...
__global__ __launch_bounds__(512, 2) void fused2_kernel(
    const float* __restrict__ ea, const int* __restrict__ srcs,
    const float* __restrict__ We, const float* __restrict__ att,
    const float* __restrict__ xl, const float* __restrict__ xr,
    const float* __restrict__ bias, const int* __restrict__ offs,
    const int* __restrict__ csr, float* __restrict__ h2out)
{
  __shared__ short W2tT[HID * 40];       // 10KB
  __shared__ short easb2[8][16 * 40];    // 10KB, all 16 rows real
  __shared__ short ee2b[8][16][136];     // 34.8KB
  int t = threadIdx.x;
  for (int i = t; i < EDGE_DIM * HID; i += 512) {
    int k = i >> 7, c = i & 127;
    W2tT[c * 40 + k] = (short)f2b(We[(size_t)k * HID + c]);
  }
  __syncthreads();
  int wave = t >> 6, lane = t & 63;
  int l15 = lane & 15, l16 = lane >> 4;
  int g = blockIdx.x * 8 + wave;          // [0, 4096)
  int c = lane * 2;
  float2 atv = *(const float2*)&att[c];
  for (int n = g; n < N_NODES; n += 4096) {
    float2 xrv = *(const float2*)&xr[(size_t)n * HID + c];
    float oa = 0.f, ob = 0.f;
    float m = 8.0f, d = 0.f;
    int beg = offs[n], end = offs[n + 1];
    int ev = 0, sv = 0;
    if (lane < 16 && beg + lane < end) { ev = csr[beg + lane]; sv = srcs[ev]; }
    for (int i0 = beg; i0 < end; i0 += 16) {
      int nv = end - i0; if (nv > 16) nv = 16;
      int sarr[16];
      #pragma unroll
      for (int j = 0; j < 16; j++) sarr[j] = __shfl(sv, j);
      float2 xv[16];
      #pragma unroll
      for (int j = 0; j < 16; j++) {
        if (j < nv) xv[j] = *(const float2*)&xl[(size_t)sarr[j] * HID + c];
        else { xv[j].x = 0.f; xv[j].y = 0.f; }
      }
      {
        int me = __shfl(ev, lane >> 2);
        int q = lane & 3;
        float4 u0 = *(const float4*)&ea[(size_t)me * EDGE_DIM + q * 8];
        float4 u1 = *(const float4*)&ea[(size_t)me * EDGE_DIM + q * 8 + 4];
        short* dst = &easb2[wave][(lane >> 2) * 40 + q * 8];
        dst[0] = (short)f2b(u0.x); dst[1] = (short)f2b(u0.y);
        dst[2] = (short)f2b(u0.z); dst[3] = (short)f2b(u0.w);
        dst[4] = (short)f2b(u1.x); dst[5] = (short)f2b(u1.y);
        dst[6] = (short)f2b(u1.z); dst[7] = (short)f2b(u1.w);
      }
      if (lane < 16 && i0 + 16 + lane < end) { ev = csr[i0 + 16 + lane]; sv = srcs[ev]; }
      bf16x8 bfrag = *(bf16x8*)&easb2[wave][l15 * 40 + l16 * 8];
      __builtin_amdgcn_s_setprio(1);     // T5
      #pragma unroll 4
      for (int tt = 0; tt < 8; tt++) {
        bf16x8 afrag = *(bf16x8*)&W2tT[(tt * 16 + l15) * 40 + l16 * 8];
        f32x4 cz = {0.f, 0.f, 0.f, 0.f};
        f32x4 cv = __builtin_amdgcn_mfma_f32_16x16x32_bf16(afrag, bfrag, cz, 0, 0, 0);
        ushort4 u;
        u.x = f2b(cv[0]); u.y = f2b(cv[1]); u.z = f2b(cv[2]); u.w = f2b(cv[3]);
        *(ushort4*)&ee2b[wave][l15][tt * 16 + l16 * 4] = u;
      }
      __builtin_amdgcn_s_setprio(0);
      float pl[16];
      #pragma unroll
      for (int j = 0; j < 16; j++) {
        ushort2 uv = *(const ushort2*)&ee2b[wave][j][c];
        float za = b2f(uv.x) + xv[j].x + xrv.x;
        float zb = b2f(uv.y) + xv[j].y + xrv.y;
        za = za > 0.f ? za : NEG_SLOPE * za;
        zb = zb > 0.f ? zb : NEG_SLOPE * zb;
        float s = za * atv.x + zb * atv.y;
        #pragma unroll
        for (int o = 1; o < 64; o <<= 1) s += __shfl_xor(s, o);
        pl[j] = (j < nv) ? s : -3.0e38f;
      }
      float cm = pl[0];
      #pragma unroll
      for (int j = 1; j < 16; j++) cm = fmaxf(cm, pl[j]);
      float mn = fmaxf(m, cm);
      if (__any(mn > m + 8.f)) {
        float fs = __expf(m - mn);
        d *= fs; oa *= fs; ob *= fs;
        m = mn;
      }
      #pragma unroll
      for (int j = 0; j < 16; j++) {
        float p = __expf(pl[j] - m);
        d += p;
        oa = fmaf(p, xv[j].x, oa);
        ob = fmaf(p, xv[j].y, ob);
      }
    }
    float invd = d > 0.f ? 1.f / d : 0.f;
    float2 o2 = make_float2(oa * invd + bias[c], ob * invd + bias[c + 1]); // no relu after conv2
    *(float2*)&h2out[(size_t)n * HID + c] = o2;
  }
}

// ---------------- MLP head ----------------
__global__ __launch_bounds__(256) void head_kernel(
    const float* __restrict__ h2, const float* __restrict__ Wh1,
    const float* __restrict__ bh1, const float* __restrict__ Wh2,
    const float* __restrict__ bh2, float* __restrict__ out)
{
  __shared__ float hs[16][HID];   // 8KB
  __shared__ float ts[16][64];    // 4KB
  int n0 = blockIdx.x * 16;
  int t = threadIdx.x;
  for (int r = 0; r < 2; r++) {
    int flat = (t + r * 256) * 4; // 2048 floats
    int i = flat >> 7, k = flat & 127;
    *(float4*)&hs[i][k] = *(const float4*)&h2[(size_t)(n0 + i) * HID + k];
  }
  __syncthreads();
  int j = t & 63, g = t >> 6;
  float acc[4];
  #pragma unroll
  for (int q = 0; q < 4; q++) acc[q] = 0.f;
  for (int k = 0; k < HID; k++) {
    float w = Wh1[k * 64 + j];
    #pragma unroll
    for (int q = 0; q < 4; q++) acc[q] = fmaf(hs[g + 4 * q][k], w, acc[q]);
  }
  float bj = bh1[j];
  #pragma unroll
  for (int q = 0; q < 4; q++) {
    float v = acc[q] + bj;
    ts[g + 4 * q][j] = v > 0.f ? v : 0.f;
  }
  __syncthreads();
  if (t < 32) {
    int nl = t >> 1, k = t & 1;
    float acc2 = bh2[k];
    for (int jj = 0; jj < 64; jj++) acc2 = fmaf(ts[nl][jj], Wh2[jj * 2 + k], acc2);
    out[(size_t)(n0 + nl) * 2 + k] = acc2;
  }
}

extern "C" void kernel_launch(void* const* d_in, const int* in_sizes, int n_in,
                              void* d_out, int out_size, void* d_ws, size_t ws_size,
                              hipStream_t stream)
{
  (void)in_sizes; (void)n_in; (void)out_size; (void)ws_size;
  const float* x    = (const float*)d_in[0];
  const int* eidx   = (const int*)d_in[1];
  const float* ea   = (const float*)d_in[2];
  const float* Wl1  = (const float*)d_in[3];
  const float* bl1  = (const float*)d_in[4];
  const float* Wr1  = (const float*)d_in[5];
  const float* br1  = (const float*)d_in[6];
  const float* We1  = (const float*)d_in[7];
  const float* att1 = (const float*)d_in[8];
  const float* bias1= (const float*)d_in[9];
  const float* Wl2  = (const float*)d_in[10];
  const float* bl2  = (const float*)d_in[11];
  const float* Wr2  = (const float*)d_in[12];
  const float* br2  = (const float*)d_in[13];
  const float* We2  = (const float*)d_in[14];
  const float* att2 = (const float*)d_in[15];
  const float* bias2= (const float*)d_in[16];
  const float* Wh1  = (const float*)d_in[17];
  const float* bh1  = (const float*)d_in[18];
  const float* Wh2  = (const float*)d_in[19];
  const float* bh2  = (const float*)d_in[20];
  const int* srcs = eidx;
  const int* dsts = eidx + N_EDGES;
  float* out = (float*)d_out;

  char* p = (char*)d_ws;
  auto alloc = [&](size_t bytes) { char* q = p; p += (bytes + 511) & ~(size_t)511; return q; };
  float*          xl1  = (float*)alloc((size_t)N_NODES * HC1 * 4);           // 41MB
  float*          xr1  = (float*)alloc((size_t)N_NODES * HC1 * 4);           // 41MB
  unsigned short* h1b  = (unsigned short*)alloc((size_t)N_NODES * HC1 * 2);  // 20.5MB
  int* deg    = (int*)alloc((size_t)N_NODES * 4);
  int* offs   = (int*)alloc((size_t)(N_NODES + 1) * 4);
  int* cursor = (int*)alloc((size_t)N_NODES * 4);
  int* csr    = (int*)alloc((size_t)N_EDGES * 4);
  unsigned short* WT1 = (unsigned short*)alloc(1024 * 64 * 2);
  unsigned short* WT2 = (unsigned short*)alloc(256 * 512 * 2);
  // xl1 region dead after fused1 -> reuse for xl2, xr2, h2 (30.7MB <= 41MB)
  float* xl2 = xl1;
  float* xr2 = xl1 + (size_t)N_NODES * HID;
  float* h2  = xl1 + (size_t)2 * N_NODES * HID;

  hipMemsetAsync(deg, 0, (size_t)N_NODES * 4, stream);
  hipLaunchKernelGGL(deg_count_kernel, dim3((N_EDGES + 255) / 256), dim3(256), 0, stream, dsts, deg);
  hipLaunchKernelGGL(wconv_kernel, dim3(512), dim3(256), 0, stream, Wl1, Wr1, Wl2, Wr2, WT1, WT2);
  hipLaunchKernelGGL(scan_kernel, dim3(1), dim3(1024), 0, stream, deg, offs, cursor);
  hipLaunchKernelGGL(scatter_kernel, dim3((N_EDGES + 255) / 256), dim3(256), 0, stream, dsts, cursor, csr);
  hipLaunchKernelGGL(linear1_kernel, dim3(N_NODES / 16), dim3(256), 0, stream,
                     x, WT1, bl1, br1, xl1, xr1);
  hipLaunchKernelGGL(fused1_kernel, dim3(1024), dim3(512), 0, stream,
                     ea, srcs, We1, att1, xl1, xr1, bias1, offs, csr, h1b);
  hipLaunchKernelGGL(linear2_kernel, dim3(N_NODES / 16), dim3(256), 0, stream,
                     h1b, WT2, bl2, br2, xl2, xr2);
  hipLaunchKernelGGL(fused2_kernel, dim3(512), dim3(512), 0, stream,
                     ea, srcs, We2, att2, xl2, xr2, bias2, offs, csr, h2);
  hipLaunchKernelGGL(head_kernel, dim3(N_NODES / 16), dim3(256), 0, stream,
                     h2, Wh1, bh1, Wh2, bh2, out);
}